// Round 6
// baseline (578.891 us; speedup 1.0000x reference)
//
#include <hip/hip_runtime.h>
#include <hip/hip_bf16.h>

#define N_TOK 4096
#define DIM   1024
#define HID   4096
#define NEXP  8
#define NPOS  8192

#define BM   256
#define BN   256
#define BKS  64                      // K-tile in shorts
#define MAXT 40                      // max m-tiles at BM=256
#define G1   (MAXT * (HID/BN))       // 640 ffn1 blocks
#define G2   (MAXT * (DIM/BN) * 4)   // 640 ffn2 blocks (split-K=4)
#define ABUF (BM*BKS)                // 16384 shorts (32 KiB)
#define BBUF (BN*BKS)

typedef float  f32x4  __attribute__((ext_vector_type(4)));
typedef __bf16 bf16x8 __attribute__((ext_vector_type(8)));
typedef unsigned short us8 __attribute__((ext_vector_type(8)));

__device__ __forceinline__ unsigned short f2bf(float f) {
  __hip_bfloat16 h = __float2bfloat16(f);
  return *reinterpret_cast<unsigned short*>(&h);
}
__device__ __forceinline__ void gload16(const void* g, void* l) {
  __builtin_amdgcn_global_load_lds(
      (const __attribute__((address_space(1))) unsigned int*)g,
      (__attribute__((address_space(3))) unsigned int*)l, 16, 0, 0);
}

// ================= 2-phase grouped-GEMM core (T3-minimum recipe) =================
// BM=BN=256, BK=64, 512 thr (8 waves 2M x 4N, per-wave out 128x64, acc[8][4]).
// LDS: 2 dbuf x (A 32K + B 32K) = 128 KiB. One __syncthreads per K-step.
// T2 swizzle: LDS[row][.] holds row's 128B with 16B-slot s at s^(row&7);
// staged via pre-swizzled GLOBAL source (LDS dest linear), read back with XOR.
template<int NKT>
__device__ __forceinline__ void gemm_core(
    const unsigned short* a0, const unsigned short* a1,
    const unsigned short* a2, const unsigned short* a3,
    const unsigned short* b0, const unsigned short* b1,
    const unsigned short* b2, const unsigned short* b3,
    unsigned short (&As)[2][ABUF], unsigned short (&Bs)[2][BBUF],
    f32x4 (&acc)[8][4])
{
  const int tid = threadIdx.x;
  const int w = tid >> 6, l = tid & 63;
  const int wr = w >> 2, wc = w & 3;           // 2 x 4 wave grid
  const int fr = l & 15;                        // fragment row/col within 16
  const int kq = (l >> 4) * 16;                 // 16B k-slot per lane quartet

  auto STAGE = [&](int t, int buf) {
    const int kt = t * BKS;
    char* Ad = (char*)&As[buf][0] + tid * 16;
    char* Bd = (char*)&Bs[buf][0] + tid * 16;
    gload16(a0 + kt, Ad);          gload16(a1 + kt, Ad + 8192);
    gload16(a2 + kt, Ad + 16384);  gload16(a3 + kt, Ad + 24576);
    gload16(b0 + kt, Bd);          gload16(b1 + kt, Bd + 8192);
    gload16(b2 + kt, Bd + 16384);  gload16(b3 + kt, Bd + 24576);
  };

  STAGE(0, 0);
  __syncthreads();

  int cur = 0;
#pragma unroll 1
  for (int t = 0; t < NKT; ++t) {
    if (t + 1 < NKT) STAGE(t + 1, cur ^ 1);
    const char* Ac = (const char*)&As[cur][0];
    const char* Bc = (const char*)&Bs[cur][0];
#pragma unroll
    for (int ks = 0; ks < 2; ++ks) {
      bf16x8 af[8], bf[4];
#pragma unroll
      for (int m = 0; m < 8; m++) {
        const int row = wr * 128 + m * 16 + fr;
        const int col = (ks * 64 + kq) ^ ((row & 7) << 4);
        af[m] = *reinterpret_cast<const bf16x8*>(Ac + row * 128 + col);
      }
#pragma unroll
      for (int n = 0; n < 4; n++) {
        const int row = wc * 64 + n * 16 + fr;
        const int col = (ks * 64 + kq) ^ ((row & 7) << 4);
        bf[n] = *reinterpret_cast<const bf16x8*>(Bc + row * 128 + col);
      }
      __builtin_amdgcn_s_setprio(1);
#pragma unroll
      for (int m = 0; m < 8; m++)
#pragma unroll
        for (int n = 0; n < 4; n++)
          acc[m][n] = __builtin_amdgcn_mfma_f32_16x16x32_bf16(af[m], bf[n], acc[m][n], 0, 0, 0);
      __builtin_amdgcn_s_setprio(0);
    }
    __syncthreads();    // drains vmcnt(0)+lgkm(0): next tile landed, cur fully read
    cur ^= 1;
  }
}

// ---------------- gating + x->bf16 (fused) ----------------
__global__ __launch_bounds__(256) void gate_kernel(
    const float* __restrict__ x, const float* __restrict__ Wg,
    const float* __restrict__ bg, int* __restrict__ topk_idx,
    float* __restrict__ topk_w, int* __restrict__ expert_count,
    unsigned short* __restrict__ xb)
{
  const int wave = threadIdx.x >> 6, lane = threadIdx.x & 63;
  const int t = blockIdx.x * 4 + wave;
  const float* xr = x + (size_t)t * DIM;
  unsigned short* xbr = xb + (size_t)t * DIM;

  float acc[NEXP];
#pragma unroll
  for (int e = 0; e < NEXP; e++) acc[e] = 0.f;
  for (int d = lane; d < DIM; d += 64) {
    float xv = xr[d];
    xbr[d] = f2bf(xv);
    const f32x4* wr = reinterpret_cast<const f32x4*>(Wg + (size_t)d * NEXP);
    f32x4 w0 = wr[0], w1 = wr[1];
    acc[0] += xv * w0.x; acc[1] += xv * w0.y; acc[2] += xv * w0.z; acc[3] += xv * w0.w;
    acc[4] += xv * w1.x; acc[5] += xv * w1.y; acc[6] += xv * w1.z; acc[7] += xv * w1.w;
  }
#pragma unroll
  for (int e = 0; e < NEXP; e++) {
#pragma unroll
    for (int off = 32; off > 0; off >>= 1)
      acc[e] += __shfl_xor(acc[e], off, 64);
  }
  if (lane == 0) {
    float s[NEXP];
#pragma unroll
    for (int e = 0; e < NEXP; e++) s[e] = acc[e] + bg[e];
    int i0 = 0; float b0 = s[0];
#pragma unroll
    for (int e = 1; e < NEXP; e++) if (s[e] > b0) { b0 = s[e]; i0 = e; }
    int i1 = -1; float b1v = -3.4e38f;
#pragma unroll
    for (int e = 0; e < NEXP; e++) if (e != i0 && s[e] > b1v) { b1v = s[e]; i1 = e; }
    float e1 = __expf(b1v - b0);
    float inv = 1.f / (1.f + e1);
    topk_idx[t*2]   = i0;  topk_idx[t*2+1] = i1;
    topk_w[t*2]     = inv; topk_w[t*2+1]   = e1 * inv;
    atomicAdd(&expert_count[i0], 1);
    atomicAdd(&expert_count[i1], 1);
  }
}

// ---------------- routing: scan + tile table + deterministic scatter ----------------
__global__ void route_kernel(const int* __restrict__ expert_count,
                             int* __restrict__ expert_offset,
                             int* __restrict__ table, int* __restrict__ nt,
                             const int* __restrict__ topk_idx,
                             const float* __restrict__ topk_w,
                             int* __restrict__ pair_token, float* __restrict__ pair_w)
{
  __shared__ int soff[NEXP];
  if (threadIdx.x == 0) {
    int off = 0, a = 0;
    for (int e = 0; e < NEXP; e++) {
      expert_offset[e] = off; soff[e] = off;
      int c = expert_count[e];
      for (int r = 0; r < c; r += BM) {
        table[a*4+0] = e; table[a*4+1] = off + r;
        table[a*4+2] = (c - r) < BM ? (c - r) : BM; a++;
      }
      off += c;
    }
    expert_offset[NEXP] = off;
    *nt = a;
  }
  __syncthreads();
  const int e = threadIdx.x >> 6;
  const int lane = threadIdx.x & 63;
  int base = soff[e];
  for (int a0 = 0; a0 < NPOS; a0 += 64) {
    int a = a0 + lane;
    int idx = topk_idx[a];
    bool f = (idx == e);
    unsigned long long m = __ballot(f);
    if (f) {
      int pos = base + __popcll(m & ((1ull << lane) - 1ull));
      pair_token[pos] = a >> 1;
      pair_w[pos]     = topk_w[a];
    }
    base += __popcll(m);
  }
}

// ---------------- weight transpose+convert [E][R][C] f32 -> [E][C][R] bf16 ------
__global__ __launch_bounds__(256) void transpose_kernel(const float* __restrict__ src,
                                                        unsigned short* __restrict__ dst,
                                                        int R, int C)
{
  __shared__ float S[64][67];
  const int e = blockIdx.z;
  const float* s = src + (size_t)e * R * C;
  unsigned short* d = dst + (size_t)e * R * C;
  const int r0 = blockIdx.y * 64, c0 = blockIdx.x * 64;
  const int tid = threadIdx.x;
  {
    const int rr = tid >> 2, cc = (tid & 3) * 16;
    const float* sp = s + (size_t)(r0 + rr) * C + c0 + cc;
#pragma unroll
    for (int j = 0; j < 4; j++) {
      f32x4 v = *reinterpret_cast<const f32x4*>(sp + j * 4);
      S[rr][cc + j*4 + 0] = v.x;
      S[rr][cc + j*4 + 1] = v.y;
      S[rr][cc + j*4 + 2] = v.z;
      S[rr][cc + j*4 + 3] = v.w;
    }
  }
  __syncthreads();
  {
    const int hh = tid >> 2, dbase = (tid & 3) * 16;
    us8 o0, o1;
#pragma unroll
    for (int i = 0; i < 8; i++) o0[i] = f2bf(S[dbase + i][hh]);
#pragma unroll
    for (int i = 0; i < 8; i++) o1[i] = f2bf(S[dbase + 8 + i][hh]);
    unsigned short* dp = d + (size_t)(c0 + hh) * R + r0 + dbase;
    *reinterpret_cast<us8*>(dp)     = o0;
    *reinterpret_cast<us8*>(dp + 8) = o1;
  }
}

// ---------------- FFN1: h = relu(xb[tok] @ Wt1^T + b1) -> bf16 ----------------
__global__ __launch_bounds__(512, 1) void ffn1_kernel(
    const unsigned short* __restrict__ xb, const unsigned short* __restrict__ Wt1,
    const float* __restrict__ b1, const int* __restrict__ pair_token,
    const int* __restrict__ table, const int* __restrict__ nt,
    unsigned short* __restrict__ h_buf)
{
  __shared__ __align__(16) unsigned short As[2][ABUF];   // 64 KiB
  __shared__ __align__(16) unsigned short Bs[2][BBUF];   // 64 KiB
  __shared__ int tok[BM];

  int wg = blockIdx.x;                         // 640 % 8 == 0 -> bijective
  wg = (wg & 7) * (G1/8) + (wg >> 3);
  const int mt = wg % MAXT;
  const int n0 = (wg / MAXT) * BN;
  if (mt >= *nt) return;
  const int e = table[mt*4+0], row_start = table[mt*4+1], rows_valid = table[mt*4+2];

  const int tid = threadIdx.x;
  if (tid < BM) tok[tid] = pair_token[row_start + (tid < rows_valid ? tid : 0)];
  __syncthreads();

  // pre-swizzled global source: stage row r = g*64 + (tid>>3), 16B slot (tid&7)^(r&7)
  const int srw = tid >> 3;
  const int soff = 8 * ((tid & 7) ^ (srw & 7));   // shorts
  const unsigned short* a0 = xb + (size_t)tok[      srw] * DIM + soff;
  const unsigned short* a1 = xb + (size_t)tok[ 64 + srw] * DIM + soff;
  const unsigned short* a2 = xb + (size_t)tok[128 + srw] * DIM + soff;
  const unsigned short* a3 = xb + (size_t)tok[192 + srw] * DIM + soff;
  const unsigned short* We = Wt1 + (size_t)e * HID * DIM;
  const unsigned short* b0 = We + (size_t)(n0 +       srw) * DIM + soff;
  const unsigned short* b1p= We + (size_t)(n0 +  64 + srw) * DIM + soff;
  const unsigned short* b2 = We + (size_t)(n0 + 128 + srw) * DIM + soff;
  const unsigned short* b3 = We + (size_t)(n0 + 192 + srw) * DIM + soff;

  f32x4 acc[8][4];
#pragma unroll
  for (int m = 0; m < 8; m++)
#pragma unroll
    for (int n = 0; n < 4; n++) acc[m][n] = (f32x4){0.f, 0.f, 0.f, 0.f};

  gemm_core<DIM/BKS>(a0, a1, a2, a3, b0, b1p, b2, b3, As, Bs, acc);

  const int w = tid >> 6, l = tid & 63;
  const int wr = w >> 2, wc = w & 3;
  const int crow = (l >> 4) * 4, ccol = l & 15;
#pragma unroll
  for (int n = 0; n < 4; n++) {
    const int cg = n0 + wc*64 + n*16 + ccol;
    const float bias = b1[(size_t)e * HID + cg];
#pragma unroll
    for (int m = 0; m < 8; m++) {
#pragma unroll
      for (int j = 0; j < 4; j++) {
        int r = wr*128 + m*16 + crow + j;
        if (r < rows_valid)
          h_buf[(size_t)(row_start + r) * HID + cg] = f2bf(fmaxf(acc[m][n][j] + bias, 0.f));
      }
    }
  }
}

// ---------------- FFN2 (split-K=4): out[t] += w * (h @ Wt2^T + b2) ----------------
__global__ __launch_bounds__(512, 1) void ffn2_kernel(
    const unsigned short* __restrict__ h_buf, const unsigned short* __restrict__ Wt2,
    const float* __restrict__ b2, const int* __restrict__ pair_token,
    const float* __restrict__ pair_w, const int* __restrict__ table,
    const int* __restrict__ nt, float* __restrict__ out)
{
  __shared__ __align__(16) unsigned short As[2][ABUF];
  __shared__ __align__(16) unsigned short Bs[2][BBUF];

  int wg = blockIdx.x;                         // 640 % 8 == 0
  wg = (wg & 7) * (G2/8) + (wg >> 3);
  const int kh  = wg / (MAXT * (DIM/BN));      // 0..3
  const int rem = wg % (MAXT * (DIM/BN));
  const int mt  = rem % MAXT;
  const int n0  = (rem / MAXT) * BN;
  if (mt >= *nt) return;
  const int e = table[mt*4+0], row_start = table[mt*4+1], rows_valid = table[mt*4+2];

  const int tid = threadIdx.x;
  const int srw = tid >> 3;
  const int soff = 8 * ((tid & 7) ^ (srw & 7));
  const int kofs = kh * (HID / 4);             // split-K offset (shorts)

  int r0 = row_start +       srw; if (r0 > NPOS-1) r0 = NPOS-1;
  int r1 = row_start +  64 + srw; if (r1 > NPOS-1) r1 = NPOS-1;
  int r2 = row_start + 128 + srw; if (r2 > NPOS-1) r2 = NPOS-1;
  int r3 = row_start + 192 + srw; if (r3 > NPOS-1) r3 = NPOS-1;

  const unsigned short* a0 = h_buf + (size_t)r0 * HID + kofs + soff;
  const unsigned short* a1 = h_buf + (size_t)r1 * HID + kofs + soff;
  const unsigned short* a2 = h_buf + (size_t)r2 * HID + kofs + soff;
  const unsigned short* a3 = h_buf + (size_t)r3 * HID + kofs + soff;
  const unsigned short* We = Wt2 + (size_t)e * DIM * HID;
  const unsigned short* b0 = We + (size_t)(n0 +       srw) * HID + kofs + soff;
  const unsigned short* b1p= We + (size_t)(n0 +  64 + srw) * HID + kofs + soff;
  const unsigned short* b2p= We + (size_t)(n0 + 128 + srw) * HID + kofs + soff;
  const unsigned short* b3 = We + (size_t)(n0 + 192 + srw) * HID + kofs + soff;

  f32x4 acc[8][4];
#pragma unroll
  for (int m = 0; m < 8; m++)
#pragma unroll
    for (int n = 0; n < 4; n++) acc[m][n] = (f32x4){0.f, 0.f, 0.f, 0.f};

  gemm_core<(HID/4)/BKS>(a0, a1, a2, a3, b0, b1p, b2p, b3, As, Bs, acc);

  const int w = tid >> 6, l = tid & 63;
  const int wr = w >> 2, wc = w & 3;
  const int crow = (l >> 4) * 4, ccol = l & 15;
  float bias[4];
#pragma unroll
  for (int n = 0; n < 4; n++)
    bias[n] = (kh == 0) ? b2[(size_t)e * DIM + n0 + wc*64 + n*16 + ccol] : 0.f;

#pragma unroll
  for (int m = 0; m < 8; m++) {
#pragma unroll
    for (int j = 0; j < 4; j++) {
      int r = wr*128 + m*16 + crow + j;
      if (r < rows_valid) {
        int pos = row_start + r;
        int t   = pair_token[pos];
        float wv = pair_w[pos];
        float* orow = out + (size_t)t * DIM;
#pragma unroll
        for (int n = 0; n < 4; n++)
          atomicAdd(&orow[n0 + wc*64 + n*16 + ccol], (acc[m][n][j] + bias[n]) * wv);
      }
    }
  }
}

extern "C" void kernel_launch(void* const* d_in, const int* in_sizes, int n_in,
                              void* d_out, int out_size, void* d_ws, size_t ws_size,
                              hipStream_t stream) {
  const float* x  = (const float*)d_in[0];
  const float* Wg = (const float*)d_in[1];
  const float* bg = (const float*)d_in[2];
  const float* W1 = (const float*)d_in[3];
  const float* b1 = (const float*)d_in[4];
  const float* W2 = (const float*)d_in[5];
  const float* b2 = (const float*)d_in[6];
  float* out = (float*)d_out;

  char* ws = (char*)d_ws;
  const size_t MB = 1024 * 1024;
  int*   expert_count  = (int*)(ws + 0);
  int*   nt            = (int*)(ws + 64);
  int*   expert_offset = (int*)(ws + 128);
  int*   table         = (int*)(ws + 256);
  int*   topk_idx      = (int*)(ws + 4096);
  float* topk_w        = (float*)(ws + 4096 + 32768);
  int*   pair_token    = (int*)(ws + 4096 + 65536);
  float* pair_w        = (float*)(ws + 4096 + 98304);
  unsigned short* xb   = (unsigned short*)(ws + 1*MB);    //  8 MiB
  unsigned short* Wt1  = (unsigned short*)(ws + 9*MB);    // 64 MiB

  const bool roomy = ws_size >= 201ull * MB;
  unsigned short* Wt2 = roomy ? (unsigned short*)(ws + 73*MB) : Wt1;
  unsigned short* h   = roomy ? (unsigned short*)(ws + 137*MB)
                              : (unsigned short*)(ws + 73*MB);

  hipMemsetAsync(ws, 0, 256, stream);
  hipMemsetAsync(d_out, 0, (size_t)N_TOK * DIM * sizeof(float), stream);

  gate_kernel<<<N_TOK / 4, 256, 0, stream>>>(x, Wg, bg, topk_idx, topk_w,
                                             expert_count, xb);
  route_kernel<<<1, 512, 0, stream>>>(expert_count, expert_offset, table, nt,
                                      topk_idx, topk_w, pair_token, pair_w);
  transpose_kernel<<<dim3(HID/64, DIM/64, NEXP), 256, 0, stream>>>(W1, Wt1, DIM, HID);
  ffn1_kernel<<<G1, 512, 0, stream>>>(xb, Wt1, b1, pair_token, table, nt, h);
  transpose_kernel<<<dim3(DIM/64, HID/64, NEXP), 256, 0, stream>>>(W2, Wt2, HID, DIM);
  ffn2_kernel<<<G2, 512, 0, stream>>>(h, Wt2, b2, pair_token, pair_w, table, nt, out);
}

// Round 7
// 485.221 us; speedup vs baseline: 1.1930x; 1.1930x over previous
//
#include <hip/hip_runtime.h>
#include <hip/hip_bf16.h>

#define N_TOK 4096
#define DIM   1024
#define HID   4096
#define NEXP  8
#define NPOS  8192

#define BK    32
#define MAXT1 40                     // BM=256 m-tiles max
#define MAXT2 72                     // BM=128 m-tiles max
#define G1    (MAXT1 * (HID/128))    // 1280 ffn1 blocks
#define G2    (MAXT2 * (DIM/128) * 2)// 1152 ffn2 blocks (split-K=2)
#define T1J   8192                   // W1 transpose 64x64 tiles: 16*64*8
#define T2J   8192                   // W2 transpose 64x64 tiles: 64*16*8

typedef float  f32x4  __attribute__((ext_vector_type(4)));
typedef __bf16 bf16x8 __attribute__((ext_vector_type(8)));
typedef unsigned short us8 __attribute__((ext_vector_type(8)));

__device__ __forceinline__ unsigned short f2bf(float f) {
  __hip_bfloat16 h = __float2bfloat16(f);
  return *reinterpret_cast<unsigned short*>(&h);
}
__device__ __forceinline__ void gload16(const void* g, void* l) {
  __builtin_amdgcn_global_load_lds(
      (const __attribute__((address_space(1))) unsigned int*)g,
      (__attribute__((address_space(3))) unsigned int*)l, 16, 0, 0);
}
#define BAR()    __builtin_amdgcn_s_barrier()
#define WAITV(n) asm volatile("s_waitcnt vmcnt(" #n ")" ::: "memory")
#define WAITL()  asm volatile("s_waitcnt lgkmcnt(0)" ::: "memory")

// ============ K1: gate (+x->bf16) fused with W1 transpose ============
// blocks [0,1024): gate 4 tokens each; [1024,1024+T1J): W1 64x64 transpose tiles
__global__ __launch_bounds__(256) void gate_t1_kernel(
    const float* __restrict__ x, const float* __restrict__ Wg,
    const float* __restrict__ bg, int* __restrict__ topk_idx,
    float* __restrict__ topk_w, int* __restrict__ expert_count,
    unsigned short* __restrict__ xb,
    const float* __restrict__ W1, unsigned short* __restrict__ Wt1)
{
  __shared__ float S[64][67];
  const int tid = threadIdx.x;
  const int bx = blockIdx.x;

  if (bx >= N_TOK/4) {               // ---- W1 transpose role: [1024][4096] -> [4096][1024]
    const int tj = bx - N_TOK/4;     // 0..8191
    const int e  = tj >> 10;
    const int rem = tj & 1023;
    const int r0 = (rem >> 6) * 64;  // over DIM (R=1024, 16 tiles)
    const int c0 = (rem & 63) * 64;  // over HID (C=4096, 64 tiles)
    const float* s = W1 + (size_t)e * DIM * HID;
    unsigned short* d = Wt1 + (size_t)e * DIM * HID;
    {
      const int rr = tid >> 2, cc = (tid & 3) * 16;
      const float* sp = s + (size_t)(r0 + rr) * HID + c0 + cc;
#pragma unroll
      for (int j = 0; j < 4; j++) {
        f32x4 v = *reinterpret_cast<const f32x4*>(sp + j * 4);
        S[rr][cc + j*4 + 0] = v.x;
        S[rr][cc + j*4 + 1] = v.y;
        S[rr][cc + j*4 + 2] = v.z;
        S[rr][cc + j*4 + 3] = v.w;
      }
    }
    __syncthreads();
    {
      const int hh = tid >> 2, dbase = (tid & 3) * 16;
      us8 o0, o1;
#pragma unroll
      for (int i = 0; i < 8; i++) o0[i] = f2bf(S[dbase + i][hh]);
#pragma unroll
      for (int i = 0; i < 8; i++) o1[i] = f2bf(S[dbase + 8 + i][hh]);
      unsigned short* dp = d + (size_t)(c0 + hh) * DIM + r0 + dbase;
      *reinterpret_cast<us8*>(dp)     = o0;
      *reinterpret_cast<us8*>(dp + 8) = o1;
    }
    return;
  }

  // ---- gate role ----
  const int wave = tid >> 6, lane = tid & 63;
  const int t = bx * 4 + wave;
  const float* xr = x + (size_t)t * DIM;
  unsigned short* xbr = xb + (size_t)t * DIM;

  float acc[NEXP];
#pragma unroll
  for (int e = 0; e < NEXP; e++) acc[e] = 0.f;
  for (int d = lane; d < DIM; d += 64) {
    float xv = xr[d];
    xbr[d] = f2bf(xv);
    const f32x4* wr = reinterpret_cast<const f32x4*>(Wg + (size_t)d * NEXP);
    f32x4 w0 = wr[0], w1 = wr[1];
    acc[0] += xv * w0.x; acc[1] += xv * w0.y; acc[2] += xv * w0.z; acc[3] += xv * w0.w;
    acc[4] += xv * w1.x; acc[5] += xv * w1.y; acc[6] += xv * w1.z; acc[7] += xv * w1.w;
  }
#pragma unroll
  for (int e = 0; e < NEXP; e++) {
#pragma unroll
    for (int off = 32; off > 0; off >>= 1)
      acc[e] += __shfl_xor(acc[e], off, 64);
  }
  if (lane == 0) {
    float s[NEXP];
#pragma unroll
    for (int e = 0; e < NEXP; e++) s[e] = acc[e] + bg[e];
    int i0 = 0; float b0 = s[0];
#pragma unroll
    for (int e = 1; e < NEXP; e++) if (s[e] > b0) { b0 = s[e]; i0 = e; }
    int i1 = -1; float b1v = -3.4e38f;
#pragma unroll
    for (int e = 0; e < NEXP; e++) if (e != i0 && s[e] > b1v) { b1v = s[e]; i1 = e; }
    float e1 = __expf(b1v - b0);
    float inv = 1.f / (1.f + e1);
    topk_idx[t*2]   = i0;  topk_idx[t*2+1] = i1;
    topk_w[t*2]     = inv; topk_w[t*2+1]   = e1 * inv;
    atomicAdd(&expert_count[i0], 1);
    atomicAdd(&expert_count[i1], 1);
  }
}

// ---------------- routing: scan + two tile tables + deterministic scatter ----------
__global__ void route_kernel(const int* __restrict__ expert_count,
                             int* __restrict__ expert_offset,
                             int* __restrict__ table1, int* __restrict__ nt1,
                             int* __restrict__ table2, int* __restrict__ nt2,
                             const int* __restrict__ topk_idx,
                             const float* __restrict__ topk_w,
                             int* __restrict__ pair_token, float* __restrict__ pair_w)
{
  __shared__ int soff[NEXP];
  if (threadIdx.x == 0) {
    int off = 0, a = 0, b = 0;
    for (int e = 0; e < NEXP; e++) {
      expert_offset[e] = off; soff[e] = off;
      int c = expert_count[e];
      for (int r = 0; r < c; r += 256) {
        table1[a*4+0] = e; table1[a*4+1] = off + r;
        table1[a*4+2] = (c - r) < 256 ? (c - r) : 256; a++;
      }
      for (int r = 0; r < c; r += 128) {
        table2[b*4+0] = e; table2[b*4+1] = off + r;
        table2[b*4+2] = (c - r) < 128 ? (c - r) : 128; b++;
      }
      off += c;
    }
    expert_offset[NEXP] = off;
    *nt1 = a; *nt2 = b;
  }
  __syncthreads();
  const int e = threadIdx.x >> 6;
  const int lane = threadIdx.x & 63;
  int base = soff[e];
  for (int a0 = 0; a0 < NPOS; a0 += 64) {
    int a = a0 + lane;
    int idx = topk_idx[a];
    bool f = (idx == e);
    unsigned long long m = __ballot(f);
    if (f) {
      int pos = base + __popcll(m & ((1ull << lane) - 1ull));
      pair_token[pos] = a >> 1;
      pair_w[pos]     = topk_w[a];
    }
    base += __popcll(m);
  }
}

// ---------------- standalone transpose (fallback path only) ----------------
__global__ __launch_bounds__(256) void transpose_kernel(const float* __restrict__ src,
                                                        unsigned short* __restrict__ dst,
                                                        int R, int C)
{
  __shared__ float S[64][67];
  const int e = blockIdx.z;
  const float* s = src + (size_t)e * R * C;
  unsigned short* d = dst + (size_t)e * R * C;
  const int r0 = blockIdx.y * 64, c0 = blockIdx.x * 64;
  const int tid = threadIdx.x;
  {
    const int rr = tid >> 2, cc = (tid & 3) * 16;
    const float* sp = s + (size_t)(r0 + rr) * C + c0 + cc;
#pragma unroll
    for (int j = 0; j < 4; j++) {
      f32x4 v = *reinterpret_cast<const f32x4*>(sp + j * 4);
      S[rr][cc + j*4 + 0] = v.x;
      S[rr][cc + j*4 + 1] = v.y;
      S[rr][cc + j*4 + 2] = v.z;
      S[rr][cc + j*4 + 3] = v.w;
    }
  }
  __syncthreads();
  {
    const int hh = tid >> 2, dbase = (tid & 3) * 16;
    us8 o0, o1;
#pragma unroll
    for (int i = 0; i < 8; i++) o0[i] = f2bf(S[dbase + i][hh]);
#pragma unroll
    for (int i = 0; i < 8; i++) o1[i] = f2bf(S[dbase + 8 + i][hh]);
    unsigned short* dp = d + (size_t)(c0 + hh) * R + r0 + dbase;
    *reinterpret_cast<us8*>(dp)     = o0;
    *reinterpret_cast<us8*>(dp + 8) = o1;
  }
}

// ============ K3: FFN1 (R3 core: BM=256 BN=128 BK=32, 512thr, dbuf) + W2 transpose ====
// role A blocks [0,G1): h = relu(xb[tok] @ Wt1^T + b1) -> bf16
// role B blocks [G1,G1+t2jobs): Wt2[E][DIM][HID] = bf16(W2[E][HID][DIM])^T, 64x64 tiles
__global__ __launch_bounds__(512) void ffn1_t2_kernel(
    const unsigned short* __restrict__ xb, const unsigned short* __restrict__ Wt1,
    const float* __restrict__ b1, const int* __restrict__ pair_token,
    const int* __restrict__ table1, const int* __restrict__ nt1,
    unsigned short* __restrict__ h_buf,
    const float* __restrict__ W2, unsigned short* __restrict__ Wt2, int t2jobs)
{
  __shared__ __align__(16) char smem[50176];
  const int tid = threadIdx.x;
  const int bx = blockIdx.x;

  if (bx >= G1) {                    // ---- W2 transpose role: [4096][1024] -> [1024][4096]
    const int tj = bx - G1;
    if (tj >= t2jobs) return;
    float (*S)[67] = (float(*)[67])smem;
    const int e   = tj >> 10;
    const int rem = tj & 1023;
    const int r0 = (rem >> 4) * 64;  // over HID (R=4096, 64 tiles)
    const int c0 = (rem & 15) * 64;  // over DIM (C=1024, 16 tiles)
    const float* s = W2 + (size_t)e * HID * DIM;
    unsigned short* d = Wt2 + (size_t)e * HID * DIM;
    {
      const int rr = tid >> 3, cc = (tid & 7) * 8;   // 512 thr: 8 f32 each
      const float* sp = s + (size_t)(r0 + rr) * DIM + c0 + cc;
      f32x4 v0 = *reinterpret_cast<const f32x4*>(sp);
      f32x4 v1 = *reinterpret_cast<const f32x4*>(sp + 4);
      S[rr][cc+0] = v0.x; S[rr][cc+1] = v0.y; S[rr][cc+2] = v0.z; S[rr][cc+3] = v0.w;
      S[rr][cc+4] = v1.x; S[rr][cc+5] = v1.y; S[rr][cc+6] = v1.z; S[rr][cc+7] = v1.w;
    }
    __syncthreads();
    {
      const int hh = tid >> 3, dbase = (tid & 7) * 8;
      us8 o;
#pragma unroll
      for (int i = 0; i < 8; i++) o[i] = f2bf(S[dbase + i][hh]);
      *reinterpret_cast<us8*>(d + (size_t)(c0 + hh) * HID + r0 + dbase) = o;
    }
    return;
  }

  // ---- ffn1 role (R3-proven core) ----
  int wg = bx;                       // 1280 % 8 == 0, bijective
  wg = (wg & 7) * (G1/8) + (wg >> 3);
  const int mt = wg % MAXT1;
  const int n0 = (wg / MAXT1) * 128;
  if (mt >= *nt1) return;
  const int e = table1[mt*4+0], row_start = table1[mt*4+1], rows_valid = table1[mt*4+2];

  unsigned short* As0 = (unsigned short*)smem;          // 256x32 = 16KB
  unsigned short* As1 = As0 + 8192;
  unsigned short* Bs0 = As1 + 8192;                     // 128x32 = 8KB
  unsigned short* Bs1 = Bs0 + 4096;
  int* tok = (int*)(smem + 49152);

  if (tid < 256) tok[tid] = pair_token[row_start + (tid < rows_valid ? tid : 0)];
  __syncthreads();

  const int w = tid >> 6, l = tid & 63;
  const int srow = w * 16 + (l >> 2);      // 0..127
  const int q8   = (l & 3) * 8;

  const unsigned short* pA0 = xb + (size_t)tok[srow] * DIM + q8;
  const unsigned short* pA1 = xb + (size_t)tok[128 + srow] * DIM + q8;
  const unsigned short* We  = Wt1 + (size_t)e * HID * DIM;
  const unsigned short* pB  = We + (size_t)(n0 + srow) * DIM + q8;
  const int wbase = w * 1024;

  f32x4 acc[4][4];
#pragma unroll
  for (int m = 0; m < 4; m++)
#pragma unroll
    for (int n = 0; n < 4; n++) acc[m][n] = (f32x4){0.f, 0.f, 0.f, 0.f};

  const int wr = w >> 1, wc = w & 1;
  const int frow = l & 15, kb = (l >> 4) * 8;

  auto STAGE = [&](int kt, unsigned short* A, unsigned short* B) {
    gload16(pA0 + kt, (char*)A + wbase);
    gload16(pA1 + kt, (char*)A + 8192 + wbase);
    gload16(pB  + kt, (char*)B + wbase);
  };
  auto COMPUTE = [&](const unsigned short* A, const unsigned short* B) {
    bf16x8 af[4], bfr[4];
#pragma unroll
    for (int m = 0; m < 4; m++)
      af[m] = *reinterpret_cast<const bf16x8*>(A + (wr*64 + m*16 + frow) * BK + kb);
#pragma unroll
    for (int n = 0; n < 4; n++)
      bfr[n] = *reinterpret_cast<const bf16x8*>(B + (wc*64 + n*16 + frow) * BK + kb);
#pragma unroll
    for (int m = 0; m < 4; m++)
#pragma unroll
      for (int n = 0; n < 4; n++)
        acc[m][n] = __builtin_amdgcn_mfma_f32_16x16x32_bf16(af[m], bfr[n], acc[m][n], 0, 0, 0);
    WAITL();
    BAR();
  };

  STAGE(0, As0, Bs0);
  int ks = BK;
  for (int i = 0; i < 15; i++) {           // 32 K-steps
    STAGE(ks, As1, Bs1); ks += BK;
    WAITV(3); BAR();
    COMPUTE(As0, Bs0);
    STAGE(ks, As0, Bs0); ks += BK;
    WAITV(3); BAR();
    COMPUTE(As1, Bs1);
  }
  STAGE(ks, As1, Bs1);
  WAITV(3); BAR();
  COMPUTE(As0, Bs0);
  WAITV(0); BAR();
  COMPUTE(As1, Bs1);

  const int crow = (l >> 4) * 4;
  const int ccol = l & 15;
#pragma unroll
  for (int n = 0; n < 4; n++) {
    const int cg = n0 + wc*64 + n*16 + ccol;
    const float bias = b1[(size_t)e * HID + cg];
#pragma unroll
    for (int m = 0; m < 4; m++) {
#pragma unroll
      for (int j = 0; j < 4; j++) {
        int r = wr*64 + m*16 + crow + j;
        if (r < rows_valid)
          h_buf[(size_t)(row_start + r) * HID + cg] = f2bf(fmaxf(acc[m][n][j] + bias, 0.f));
      }
    }
  }
}

// ============ K4: FFN2 (R3 core: BM=128 BN=128 BK=32, 256thr, dbuf), split-K=2 ======
__global__ __launch_bounds__(256) void ffn2_kernel(
    const unsigned short* __restrict__ h_buf, const unsigned short* __restrict__ Wt2,
    const float* __restrict__ b2, const int* __restrict__ pair_token,
    const float* __restrict__ pair_w, const int* __restrict__ table2,
    const int* __restrict__ nt2, float* __restrict__ out)
{
  int wg = blockIdx.x;                       // 1152 % 8 == 0
  wg = (wg & 7) * (G2/8) + (wg >> 3);
  const int kh  = wg / (MAXT2 * 8);          // 0..1
  const int rem = wg % (MAXT2 * 8);
  const int mt  = rem % MAXT2;
  const int n0  = (rem / MAXT2) * 128;
  if (mt >= *nt2) return;
  const int e = table2[mt*4+0], row_start = table2[mt*4+1], rows_valid = table2[mt*4+2];

  __shared__ __align__(16) unsigned short As0[128*BK], As1[128*BK];
  __shared__ __align__(16) unsigned short Bs0[128*BK], Bs1[128*BK];

  const int tid = threadIdx.x;
  const int w = tid >> 6, l = tid & 63;
  const int srow = w * 16 + (l >> 2);        // 0..63
  const int q8   = (l & 3) * 8;
  const int kofs = kh * (HID / 2);           // split-K offset (shorts)

  int ar0 = row_start + srow;       if (ar0 > NPOS - 1) ar0 = NPOS - 1;
  int ar1 = row_start + 64 + srow;  if (ar1 > NPOS - 1) ar1 = NPOS - 1;

  const unsigned short* pA0 = h_buf + (size_t)ar0 * HID + kofs + q8;
  const unsigned short* pA1 = h_buf + (size_t)ar1 * HID + kofs + q8;
  const unsigned short* We  = Wt2 + (size_t)e * DIM * HID;
  const unsigned short* pB0 = We + (size_t)(n0 + srow) * HID + kofs + q8;
  const unsigned short* pB1 = We + (size_t)(n0 + 64 + srow) * HID + kofs + q8;
  const int wbase = w * 1024;

  f32x4 acc[4][4];
#pragma unroll
  for (int m = 0; m < 4; m++)
#pragma unroll
    for (int n = 0; n < 4; n++) acc[m][n] = (f32x4){0.f, 0.f, 0.f, 0.f};

  const int wr = w >> 1, wc = w & 1;
  const int frow = l & 15, kb = (l >> 4) * 8;

  auto STAGE = [&](int kt, unsigned short* A, unsigned short* B) {
    gload16(pA0 + kt, (char*)A + wbase);
    gload16(pA1 + kt, (char*)A + 4096 + wbase);
    gload16(pB0 + kt, (char*)B + wbase);
    gload16(pB1 + kt, (char*)B + 4096 + wbase);
  };
  auto COMPUTE = [&](const unsigned short* A, const unsigned short* B) {
    bf16x8 af[4], bfr[4];
#pragma unroll
    for (int m = 0; m < 4; m++)
      af[m] = *reinterpret_cast<const bf16x8*>(A + (wr*64 + m*16 + frow) * BK + kb);
#pragma unroll
    for (int n = 0; n < 4; n++)
      bfr[n] = *reinterpret_cast<const bf16x8*>(B + (wc*64 + n*16 + frow) * BK + kb);
#pragma unroll
    for (int m = 0; m < 4; m++)
#pragma unroll
      for (int n = 0; n < 4; n++)
        acc[m][n] = __builtin_amdgcn_mfma_f32_16x16x32_bf16(af[m], bfr[n], acc[m][n], 0, 0, 0);
    WAITL();
    BAR();
  };

  STAGE(0, As0, Bs0);
  int ks = BK;
  for (int i = 0; i < 31; i++) {             // 64 K-steps (K=2048)
    STAGE(ks, As1, Bs1); ks += BK;
    WAITV(4); BAR();
    COMPUTE(As0, Bs0);
    STAGE(ks, As0, Bs0); ks += BK;
    WAITV(4); BAR();
    COMPUTE(As1, Bs1);
  }
  STAGE(ks, As1, Bs1);
  WAITV(4); BAR();
  COMPUTE(As0, Bs0);
  WAITV(0); BAR();
  COMPUTE(As1, Bs1);

  const int crow = (l >> 4) * 4;
  const int ccol = l & 15;
  float bias[4];
#pragma unroll
  for (int n = 0; n < 4; n++)
    bias[n] = (kh == 0) ? b2[(size_t)e * DIM + n0 + wc*64 + n*16 + ccol] : 0.f;

#pragma unroll
  for (int m = 0; m < 4; m++) {
#pragma unroll
    for (int j = 0; j < 4; j++) {
      int r = wr*64 + m*16 + crow + j;
      if (r < rows_valid) {
        int pos = row_start + r;
        int t   = pair_token[pos];
        float wv = pair_w[pos];
        float* orow = out + (size_t)t * DIM;
#pragma unroll
        for (int n = 0; n < 4; n++)
          atomicAdd(&orow[n0 + wc*64 + n*16 + ccol], (acc[m][n][j] + bias[n]) * wv);
      }
    }
  }
}

extern "C" void kernel_launch(void* const* d_in, const int* in_sizes, int n_in,
                              void* d_out, int out_size, void* d_ws, size_t ws_size,
                              hipStream_t stream) {
  const float* x  = (const float*)d_in[0];
  const float* Wg = (const float*)d_in[1];
  const float* bg = (const float*)d_in[2];
  const float* W1 = (const float*)d_in[3];
  const float* b1 = (const float*)d_in[4];
  const float* W2 = (const float*)d_in[5];
  const float* b2 = (const float*)d_in[6];
  float* out = (float*)d_out;

  char* ws = (char*)d_ws;
  const size_t MB = 1024 * 1024;
  int*   expert_count  = (int*)(ws + 0);
  int*   nt1           = (int*)(ws + 64);
  int*   nt2           = (int*)(ws + 68);
  int*   expert_offset = (int*)(ws + 128);
  int*   table1        = (int*)(ws + 1024);
  int*   table2        = (int*)(ws + 2048);
  int*   topk_idx      = (int*)(ws + 4096);
  float* topk_w        = (float*)(ws + 4096 + 32768);
  int*   pair_token    = (int*)(ws + 4096 + 65536);
  float* pair_w        = (float*)(ws + 4096 + 98304);
  unsigned short* xb   = (unsigned short*)(ws + 1*MB);    //  8 MiB
  unsigned short* Wt1  = (unsigned short*)(ws + 9*MB);    // 64 MiB

  const bool roomy = ws_size >= 201ull * MB;
  unsigned short* Wt2 = roomy ? (unsigned short*)(ws + 73*MB) : Wt1;
  unsigned short* h   = roomy ? (unsigned short*)(ws + 137*MB)
                              : (unsigned short*)(ws + 73*MB);

  hipMemsetAsync(ws, 0, 256, stream);
  hipMemsetAsync(d_out, 0, (size_t)N_TOK * DIM * sizeof(float), stream);

  // K1: gate + x->bf16 + W1 transpose
  gate_t1_kernel<<<N_TOK/4 + T1J, 256, 0, stream>>>(x, Wg, bg, topk_idx, topk_w,
                                                    expert_count, xb, W1, Wt1);
  // K2: routing
  route_kernel<<<1, 512, 0, stream>>>(expert_count, expert_offset, table1, nt1,
                                      table2, nt2, topk_idx, topk_w,
                                      pair_token, pair_w);
  // K3: ffn1 (+ W2 transpose fused when workspace allows)
  if (roomy) {
    ffn1_t2_kernel<<<G1 + T2J, 512, 0, stream>>>(xb, Wt1, b1, pair_token, table1,
                                                 nt1, h, W2, Wt2, T2J);
  } else {
    ffn1_t2_kernel<<<G1, 512, 0, stream>>>(xb, Wt1, b1, pair_token, table1,
                                           nt1, h, W2, Wt2, 0);
    transpose_kernel<<<dim3(DIM/64, HID/64, NEXP), 256, 0, stream>>>(W2, Wt2, HID, DIM);
  }
  // K4: ffn2 split-K=2 with atomic combine
  ffn2_kernel<<<G2, 256, 0, stream>>>(h, Wt2, b2, pair_token, pair_w, table2, nt2, out);
}